// Round 1
// baseline (370.322 us; speedup 1.0000x reference)
//
#include <hip/hip_runtime.h>
#include <hip/hip_bf16.h>

#define N_NODES 100000
#define IN_DIM 128
#define HID_DIM 128
#define N_EDGES 1600000

// ---------------- edge-index format probe -------------------------------
// Reference edge_index is int64. Harness contract says ints arrive as int32,
// but hedge: if the buffer is really int64 (little-endian), every odd 32-bit
// word of the first 64 values is 0 (ids < 2^31). Probability of that for
// genuine int32 ids is ~0.
__global__ void k_detect(const int* __restrict__ ei, int* __restrict__ flag) {
    int lane = threadIdx.x & 63;
    int w = ei[2 * lane + 1];
    int all0 = __all(w == 0);
    if (threadIdx.x == 0) *flag = all0;   // 1 => int64 layout
}

__device__ __forceinline__ int load_src(const int* ei, int is64, int e) {
    return is64 ? ei[2 * (size_t)e] : ei[e];
}
__device__ __forceinline__ int load_dst(const int* ei, int is64, int e) {
    return is64 ? ei[2 * ((size_t)N_EDGES + e)] : ei[N_EDGES + e];
}

// ---------------- init ---------------------------------------------------
__global__ void k_init(int* __restrict__ cnt, int* __restrict__ cursor,
                       int* __restrict__ total) {
    int i = blockIdx.x * blockDim.x + threadIdx.x;
    if (i < N_NODES) { cnt[i] = 0; cursor[i] = 0; }
    if (i == 0) *total = 0;
}

// ---------------- in-degree count (dst) ----------------------------------
__global__ void k_count(const int* __restrict__ ei, const int* __restrict__ flag,
                        int* __restrict__ cnt) {
    int e = blockIdx.x * blockDim.x + threadIdx.x;
    if (e < N_EDGES) {
        int d = load_dst(ei, *flag, e);
        atomicAdd(&cnt[d], 1);
    }
}

// ---------------- dinv + segment offsets (wave scan + one atomic/wave) ---
__global__ void k_offsets(const int* __restrict__ cnt, float* __restrict__ dinv,
                          int* __restrict__ row_start, int* __restrict__ total) {
    int i = blockIdx.x * blockDim.x + threadIdx.x;
    int lane = threadIdx.x & 63;
    int c = (i < N_NODES) ? cnt[i] : 0;
    if (i < N_NODES) dinv[i] = rsqrtf((float)(c + 1));   // +1 self loop
    int v = c;
#pragma unroll
    for (int d = 1; d < 64; d <<= 1) {
        int t = __shfl_up(v, d);
        if (lane >= d) v += t;
    }
    int base = 0;
    if (lane == 63) base = atomicAdd(total, v);
    base = __shfl(base, 63);
    if (i < N_NODES) row_start[i] = base + v - c;        // exclusive within wave
}

// ---------------- CSR fill ------------------------------------------------
__global__ void k_fill(const int* __restrict__ ei, const int* __restrict__ flag,
                       const int* __restrict__ row_start, int* __restrict__ cursor,
                       int* __restrict__ csr_src) {
    int e = blockIdx.x * blockDim.x + threadIdx.x;
    if (e < N_EDGES) {
        int is64 = *flag;
        int s = load_src(ei, is64, e);
        int d = load_dst(ei, is64, e);
        int pos = atomicAdd(&cursor[d], 1);
        csr_src[row_start[d] + pos] = s;
    }
}

// ---------------- GEMM: h = x @ W  (f32 VALU, register-blocked) -----------
// 64 rows x 128 cols per block, 256 threads, 8x4 acc/thread, BK=32.
__global__ __launch_bounds__(256) void k_gemm(const float* __restrict__ x,
                                              const float* __restrict__ w,
                                              float* __restrict__ h) {
    __shared__ float xs[32][68];    // [k][row], padded for bank spread
    __shared__ float ws[32][132];   // [k][col], padded (132%4==0 keeps b128 align)
    const int tid = threadIdx.x;
    const int block_row = blockIdx.x * 64;
    const int tcol = tid & 31;
    const int trow = tid >> 5;
    const int c0 = tcol * 4;
    const int r0 = trow * 8;
    float acc[8][4] = {};

    for (int k0 = 0; k0 < IN_DIM; k0 += 32) {
        {   // stage x tile transposed: thread -> row=t&63, k-group=(t>>6)*8
            int row = tid & 63;
            int kk = (tid >> 6) * 8;
            int grow = block_row + row;
            if (grow > N_NODES - 1) grow = N_NODES - 1;   // clamp, stores guarded
            const float4* p =
                reinterpret_cast<const float4*>(&x[(size_t)grow * IN_DIM + k0 + kk]);
            float4 a = p[0], b = p[1];
            xs[kk + 0][row] = a.x; xs[kk + 1][row] = a.y;
            xs[kk + 2][row] = a.z; xs[kk + 3][row] = a.w;
            xs[kk + 4][row] = b.x; xs[kk + 5][row] = b.y;
            xs[kk + 6][row] = b.z; xs[kk + 7][row] = b.w;
        }
        {   // stage W tile row-major
            int kq = tid >> 3;            // 0..31
            int cc = (tid & 7) * 16;      // 0..112
            const float4* p =
                reinterpret_cast<const float4*>(&w[(size_t)(k0 + kq) * HID_DIM + cc]);
            float4* q = reinterpret_cast<float4*>(&ws[kq][cc]);
            q[0] = p[0]; q[1] = p[1]; q[2] = p[2]; q[3] = p[3];
        }
        __syncthreads();
#pragma unroll
        for (int k = 0; k < 32; ++k) {
            float4 b  = *reinterpret_cast<const float4*>(&ws[k][c0]);
            float4 aL = *reinterpret_cast<const float4*>(&xs[k][r0]);
            float4 aH = *reinterpret_cast<const float4*>(&xs[k][r0 + 4]);
            float a[8] = {aL.x, aL.y, aL.z, aL.w, aH.x, aH.y, aH.z, aH.w};
#pragma unroll
            for (int r = 0; r < 8; ++r) {
                acc[r][0] = fmaf(a[r], b.x, acc[r][0]);
                acc[r][1] = fmaf(a[r], b.y, acc[r][1]);
                acc[r][2] = fmaf(a[r], b.z, acc[r][2]);
                acc[r][3] = fmaf(a[r], b.w, acc[r][3]);
            }
        }
        __syncthreads();
    }
#pragma unroll
    for (int r = 0; r < 8; ++r) {
        int grow = block_row + r0 + r;
        if (grow < N_NODES) {
            float4 v = make_float4(acc[r][0], acc[r][1], acc[r][2], acc[r][3]);
            *reinterpret_cast<float4*>(&h[(size_t)grow * HID_DIM + c0]) = v;
        }
    }
}

// ---------------- gather: one wave per node, fused norm+bias+ReLU ---------
__global__ __launch_bounds__(256) void k_gather(const float* __restrict__ h,
                                                const int* __restrict__ csr_src,
                                                const int* __restrict__ row_start,
                                                const int* __restrict__ cnt,
                                                const float* __restrict__ dinv,
                                                const float* __restrict__ bias,
                                                float* __restrict__ out) {
    int gw = (blockIdx.x * blockDim.x + threadIdx.x) >> 6;
    int lane = threadIdx.x & 63;
    if (gw >= N_NODES) return;
    const int i = gw;
    const int rs = row_start[i];
    const int n = cnt[i];
    const float di = dinv[i];

    // self loop: contributes di*h_i to acc (multiplied by di at the end)
    float2 hv = *reinterpret_cast<const float2*>(&h[(size_t)i * HID_DIM + 2 * lane]);
    float2 acc;
    acc.x = di * hv.x;
    acc.y = di * hv.y;

    for (int e0 = 0; e0 < n; e0 += 64) {
        int m = n - e0; if (m > 64) m = 64;
        int idx = rs + e0 + (lane < m ? lane : m - 1);
        int se = csr_src[idx];        // lane-parallel edge prefetch
        float dse = dinv[se];         // lane-parallel dinv gather
        for (int j = 0; j < m; ++j) {
            int s = __shfl(se, j);
            float ds = __shfl(dse, j);
            float2 v = *reinterpret_cast<const float2*>(&h[(size_t)s * HID_DIM + 2 * lane]);
            acc.x = fmaf(ds, v.x, acc.x);
            acc.y = fmaf(ds, v.y, acc.y);
        }
    }
    float2 bv = reinterpret_cast<const float2*>(bias)[lane];
    float2 o;
    o.x = fmaxf(fmaf(di, acc.x, bv.x), 0.0f);
    o.y = fmaxf(fmaf(di, acc.y, bv.y), 0.0f);
    *reinterpret_cast<float2*>(&out[(size_t)i * HID_DIM + 2 * lane]) = o;
}

// ---------------- launcher -------------------------------------------------
extern "C" void kernel_launch(void* const* d_in, const int* in_sizes, int n_in,
                              void* d_out, int out_size, void* d_ws, size_t ws_size,
                              hipStream_t stream) {
    const float* x    = (const float*)d_in[0];
    const int*   ei   = (const int*)d_in[1];
    const float* w    = (const float*)d_in[2];
    const float* bias = (const float*)d_in[3];
    float* out = (float*)d_out;

    // workspace layout (bytes), all 16B-aligned; total ~59.3 MB
    char* wsb = (char*)d_ws;
    float* h         = (float*)(wsb);                 // 100000*128*4 = 51,200,000
    int*   cnt       = (int*)(wsb + 51200000);        // 400,000
    float* dinv      = (float*)(wsb + 51600000);      // 400,000
    int*   row_start = (int*)(wsb + 52000000);        // 400,000
    int*   cursor    = (int*)(wsb + 52400000);        // 400,000
    int*   csr_src   = (int*)(wsb + 52800000);        // 6,400,000
    int*   total     = (int*)(wsb + 59200000);        // 16
    int*   flag      = (int*)(wsb + 59200016);        // 16

    k_detect<<<1, 64, 0, stream>>>(ei, flag);
    k_init<<<(N_NODES + 255) / 256, 256, 0, stream>>>(cnt, cursor, total);
    k_count<<<(N_EDGES + 255) / 256, 256, 0, stream>>>(ei, flag, cnt);
    k_offsets<<<(N_NODES + 255) / 256, 256, 0, stream>>>(cnt, dinv, row_start, total);
    k_fill<<<(N_EDGES + 255) / 256, 256, 0, stream>>>(ei, flag, row_start, cursor, csr_src);
    k_gemm<<<(N_NODES + 63) / 64, 256, 0, stream>>>(x, w, h);
    k_gather<<<(N_NODES + 3) / 4, 256, 0, stream>>>(h, csr_src, row_start, cnt, dinv, bias, out);
}

// Round 3
// 285.290 us; speedup vs baseline: 1.2981x; 1.2981x over previous
//
#include <hip/hip_runtime.h>
#include <hip/hip_bf16.h>

#define N_NODES 100000
#define IN_DIM 128
#define HID_DIM 128
#define N_EDGES 1600000

using short8 = __attribute__((ext_vector_type(8))) short;
using f32x4  = __attribute__((ext_vector_type(4))) float;

// ---- bf16 helpers (bit ops, RNE encode) ----------------------------------
__device__ __forceinline__ unsigned short f2bf(float f) {
    unsigned int b = __float_as_uint(f);
    b += 0x7FFFu + ((b >> 16) & 1u);
    return (unsigned short)(b >> 16);
}
__device__ __forceinline__ float bf2f(unsigned short u) {
    return __uint_as_float((unsigned int)u << 16);
}

// ---------------- edge-index format probe ---------------------------------
__global__ void k_detect(const int* __restrict__ ei, int* __restrict__ flag) {
    int lane = threadIdx.x & 63;
    int w = ei[2 * lane + 1];
    int all0 = __all(w == 0);
    if (threadIdx.x == 0) *flag = all0;   // 1 => int64 layout
}

// ---------------- init -----------------------------------------------------
__global__ void k_init(int* __restrict__ cnt, int* __restrict__ cursor,
                       int* __restrict__ total) {
    int i = blockIdx.x * blockDim.x + threadIdx.x;
    if (i < N_NODES) { cnt[i] = 0; cursor[i] = 0; }
    if (i == 0) *total = 0;
}

// ---------------- W -> Wt bf16 (transposed, [col][k]) ----------------------
__global__ void k_wconv(const float* __restrict__ w, unsigned short* __restrict__ wt) {
    int t = threadIdx.x;
    for (int e = 0; e < 64; ++e) {
        int i = e * 256 + t;              // coalesced read
        int k = i >> 7, c = i & 127;
        wt[c * 128 + k] = f2bf(w[i]);
    }
}

// ---------------- in-degree count (dst), 2 edges/thread --------------------
__global__ void k_count(const int* __restrict__ ei, const int* __restrict__ flag,
                        int* __restrict__ cnt) {
    int t = blockIdx.x * blockDim.x + threadIdx.x;
    if (t >= N_EDGES / 2) return;
    int is64 = *flag;
    int d0, d1;
    if (is64) {
        int4 v = reinterpret_cast<const int4*>(ei + 2 * (size_t)N_EDGES)[t];
        d0 = v.x; d1 = v.z;
    } else {
        int2 v = reinterpret_cast<const int2*>(ei + N_EDGES)[t];
        d0 = v.x; d1 = v.y;
    }
    atomicAdd(&cnt[d0], 1);
    atomicAdd(&cnt[d1], 1);
}

// ---------------- dinv + segment offsets (wave scan) -----------------------
__global__ void k_offsets(const int* __restrict__ cnt, float* __restrict__ dinv,
                          int* __restrict__ row_start, int* __restrict__ total) {
    int i = blockIdx.x * blockDim.x + threadIdx.x;
    int lane = threadIdx.x & 63;
    int c = (i < N_NODES) ? cnt[i] : 0;
    if (i < N_NODES) dinv[i] = rsqrtf((float)(c + 1));   // +1 self loop
    int v = c;
#pragma unroll
    for (int d = 1; d < 64; d <<= 1) {
        int t = __shfl_up(v, d);
        if (lane >= d) v += t;
    }
    int base = 0;
    if (lane == 63) base = atomicAdd(total, v);
    base = __shfl(base, 63);
    if (i < N_NODES) row_start[i] = base + v - c;
}

// ---------------- CSR fill, 2 edges/thread ---------------------------------
__global__ void k_fill(const int* __restrict__ ei, const int* __restrict__ flag,
                       const int* __restrict__ row_start, int* __restrict__ cursor,
                       int* __restrict__ csr_src) {
    int t = blockIdx.x * blockDim.x + threadIdx.x;
    if (t >= N_EDGES / 2) return;
    int is64 = *flag;
    int s0, s1, d0, d1;
    if (is64) {
        int4 vs = reinterpret_cast<const int4*>(ei)[t];
        int4 vd = reinterpret_cast<const int4*>(ei + 2 * (size_t)N_EDGES)[t];
        s0 = vs.x; s1 = vs.z; d0 = vd.x; d1 = vd.z;
    } else {
        int2 vs = reinterpret_cast<const int2*>(ei)[t];
        int2 vd = reinterpret_cast<const int2*>(ei + N_EDGES)[t];
        s0 = vs.x; s1 = vs.y; d0 = vd.x; d1 = vd.y;
    }
    int p0 = atomicAdd(&cursor[d0], 1);
    csr_src[row_start[d0] + p0] = s0;
    int p1 = atomicAdd(&cursor[d1], 1);
    csr_src[row_start[d1] + p1] = s1;
}

// ---------------- GEMM: h(bf16) = x(f32->bf16) @ W ------------------------
// BM=64 rows/block, 256 threads = 4 waves, each wave 16 rows x 128 cols.
// mfma_f32_16x16x32_bf16: A row=l&15, k=(l>>4)*8+j ; B col=l&15, same k ;
// D col=l&15, row=(l>>4)*4+reg  [per m89].
#define LDK 136   // padded bf16 row length (272 B -> 2-way LDS aliasing = free)
__global__ __launch_bounds__(256) void k_gemm(const float* __restrict__ x,
                                              const unsigned short* __restrict__ wt,
                                              unsigned short* __restrict__ h) {
    __shared__ unsigned short xs[64 * LDK];     // A tile  [row][k]
    __shared__ unsigned short ws[128 * LDK];    // B tile  [col][k] (Wt layout)
    const int tid = threadIdx.x;
    const int brow = blockIdx.x * 64;

    {   // stage x: 4 threads/row, 32 f32 each -> bf16
        int row = tid >> 2;
        int seg = (tid & 3) * 32;
        int grow = brow + row; if (grow > N_NODES - 1) grow = N_NODES - 1;
        const float4* p = reinterpret_cast<const float4*>(&x[(size_t)grow * IN_DIM + seg]);
#pragma unroll
        for (int i = 0; i < 8; ++i) {
            float4 v = p[i];
            ushort4 u = make_ushort4(f2bf(v.x), f2bf(v.y), f2bf(v.z), f2bf(v.w));
            *reinterpret_cast<ushort4*>(&xs[row * LDK + seg + i * 4]) = u;
        }
    }
    {   // stage Wt: 2 threads per 128-wide col-row, 64 bf16 each (8 x short8)
        int row = tid >> 1;
        int seg = (tid & 1) * 64;
        const short8* p = reinterpret_cast<const short8*>(&wt[row * 128 + seg]);
#pragma unroll
        for (int i = 0; i < 8; ++i)
            *reinterpret_cast<short8*>(&ws[row * LDK + seg + i * 8]) = p[i];
    }
    __syncthreads();

    const int lane = tid & 63;
    const int wid  = tid >> 6;
    const int m0   = wid * 16;
    const int arow = m0 + (lane & 15);
    const int kgrp = (lane >> 4) * 8;
    f32x4 acc[8] = {};

#pragma unroll
    for (int k0 = 0; k0 < 128; k0 += 32) {
        short8 a = *reinterpret_cast<const short8*>(&xs[arow * LDK + k0 + kgrp]);
#pragma unroll
        for (int nb = 0; nb < 8; ++nb) {
            short8 b = *reinterpret_cast<const short8*>(
                &ws[(nb * 16 + (lane & 15)) * LDK + k0 + kgrp]);
            acc[nb] = __builtin_amdgcn_mfma_f32_16x16x32_bf16(a, b, acc[nb], 0, 0, 0);
        }
    }

#pragma unroll
    for (int nb = 0; nb < 8; ++nb) {
#pragma unroll
        for (int r = 0; r < 4; ++r) {
            int node = brow + m0 + (lane >> 4) * 4 + r;
            int feat = nb * 16 + (lane & 15);
            if (node < N_NODES) h[(size_t)node * HID_DIM + feat] = f2bf(acc[nb][r]);
        }
    }
}

// ---------------- gather: 1 wave/node, 4 edges in flight, bf16 h -----------
__global__ __launch_bounds__(256) void k_gather(const unsigned short* __restrict__ h,
                                                const int* __restrict__ csr_src,
                                                const int* __restrict__ row_start,
                                                const int* __restrict__ cnt,
                                                const float* __restrict__ dinv,
                                                const float* __restrict__ bias,
                                                float* __restrict__ out) {
    int node = (blockIdx.x * blockDim.x + threadIdx.x) >> 6;
    if (node >= N_NODES) return;
    const int lane = threadIdx.x & 63;
    const int q  = lane >> 4;        // quarter: which edge slot this lane serves
    const int l4 = lane & 15;        // feature group: feats 8*l4 .. 8*l4+7
    const int rs = row_start[node];
    const int n  = cnt[node];
    const float di = dinv[node];
    const int total = n + 1;         // + self loop (virtual last slot)

    float acc[8] = {};

    for (int e0 = 0; e0 < total; e0 += 64) {
        int rem = total - e0;
        int m = rem < 64 ? rem : 64;
        // lane-parallel prefetch of up to 64 slot (src, weight) pairs
        int t = e0 + lane;
        int tt = t <= n ? t : n;
        int se; float dse;
        if (tt < n) { se = csr_src[rs + tt]; dse = dinv[se]; }
        else        { se = node;             dse = di; }     // self slot
        if (t > n) dse = 0.0f;                               // padding
        int mm = (m + 3) & ~3;
        for (int j = 0; j < mm; j += 4) {
            int   s  = __shfl(se,  j + q);
            float ds = __shfl(dse, j + q);
            short8 v = *reinterpret_cast<const short8*>(&h[(size_t)s * HID_DIM + l4 * 8]);
#pragma unroll
            for (int b = 0; b < 8; ++b)
                acc[b] = fmaf(ds, bf2f((unsigned short)v[b]), acc[b]);
        }
    }

    // combine the 4 quarters (each held partial sums for the same features)
#pragma unroll
    for (int b = 0; b < 8; ++b) {
        acc[b] += __shfl_xor(acc[b], 16);
        acc[b] += __shfl_xor(acc[b], 32);
    }

    if (q == 0) {
        float4 bv = *reinterpret_cast<const float4*>(&bias[l4 * 8]);
        float4 o;
        o.x = fmaxf(fmaf(di, acc[0], bv.x), 0.0f);
        o.y = fmaxf(fmaf(di, acc[1], bv.y), 0.0f);
        o.z = fmaxf(fmaf(di, acc[2], bv.z), 0.0f);
        o.w = fmaxf(fmaf(di, acc[3], bv.w), 0.0f);
        *reinterpret_cast<float4*>(&out[(size_t)node * HID_DIM + l4 * 8]) = o;
    } else if (q == 1) {
        float4 bv = *reinterpret_cast<const float4*>(&bias[l4 * 8 + 4]);
        float4 o;
        o.x = fmaxf(fmaf(di, acc[4], bv.x), 0.0f);
        o.y = fmaxf(fmaf(di, acc[5], bv.y), 0.0f);
        o.z = fmaxf(fmaf(di, acc[6], bv.z), 0.0f);
        o.w = fmaxf(fmaf(di, acc[7], bv.w), 0.0f);
        *reinterpret_cast<float4*>(&out[(size_t)node * HID_DIM + l4 * 8 + 4]) = o;
    }
}

// ---------------- launcher --------------------------------------------------
extern "C" void kernel_launch(void* const* d_in, const int* in_sizes, int n_in,
                              void* d_out, int out_size, void* d_ws, size_t ws_size,
                              hipStream_t stream) {
    const float* x    = (const float*)d_in[0];
    const int*   ei   = (const int*)d_in[1];
    const float* w    = (const float*)d_in[2];
    const float* bias = (const float*)d_in[3];
    float* out = (float*)d_out;

    // workspace layout (bytes), 16B-aligned; ~33.7 MB total
    char* wsb = (char*)d_ws;
    unsigned short* h   = (unsigned short*)(wsb);           // 25,600,000
    int*   cnt       = (int*)(wsb + 25600000);              // 400,000
    float* dinv      = (float*)(wsb + 26000000);            // 400,000
    int*   row_start = (int*)(wsb + 26400000);              // 400,000
    int*   cursor    = (int*)(wsb + 26800000);              // 400,000
    int*   csr_src   = (int*)(wsb + 27200000);              // 6,400,000
    unsigned short* wt = (unsigned short*)(wsb + 33600000); // 32,768
    int*   total     = (int*)(wsb + 33632768);              // 16
    int*   flag      = (int*)(wsb + 33632784);              // 16

    k_detect <<<1, 64, 0, stream>>>(ei, flag);
    k_init   <<<(N_NODES + 255) / 256, 256, 0, stream>>>(cnt, cursor, total);
    k_wconv  <<<1, 256, 0, stream>>>(w, wt);
    k_count  <<<(N_EDGES / 2 + 255) / 256, 256, 0, stream>>>(ei, flag, cnt);
    k_offsets<<<(N_NODES + 255) / 256, 256, 0, stream>>>(cnt, dinv, row_start, total);
    k_fill   <<<(N_EDGES / 2 + 255) / 256, 256, 0, stream>>>(ei, flag, row_start, cursor, csr_src);
    k_gemm   <<<(N_NODES + 63) / 64, 256, 0, stream>>>(x, wt, h);
    k_gather <<<(N_NODES + 3) / 4, 256, 0, stream>>>(h, csr_src, row_start, cnt, dinv, bias, out);
}

// Round 4
// 244.269 us; speedup vs baseline: 1.5160x; 1.1679x over previous
//
#include <hip/hip_runtime.h>
#include <hip/hip_bf16.h>

#define N_NODES 100000
#define IN_DIM 128
#define HID_DIM 128
#define N_EDGES 1600000
#define NB 196          // ceil(1.6e6 / 8192) buckets; each = 32KB csr window
#define BK_EDGES 4096   // edges staged per k_bin block

using short8 = __attribute__((ext_vector_type(8))) short;
using f32x4  = __attribute__((ext_vector_type(4))) float;

// ---- bf16 helpers (bit ops, RNE encode) ----------------------------------
__device__ __forceinline__ unsigned short f2bf(float f) {
    unsigned int b = __float_as_uint(f);
    b += 0x7FFFu + ((b >> 16) & 1u);
    return (unsigned short)(b >> 16);
}
__device__ __forceinline__ float bf2f(unsigned short u) {
    return __uint_as_float((unsigned int)u << 16);
}

// ---------------- edge-index format probe ---------------------------------
__global__ void k_detect(const int* __restrict__ ei, int* __restrict__ flag) {
    int lane = threadIdx.x & 63;
    int w = ei[2 * lane + 1];
    int all0 = __all(w == 0);
    if (threadIdx.x == 0) *flag = all0;   // 1 => int64 layout
}

// ---------------- init -----------------------------------------------------
__global__ void k_init(int* __restrict__ cnt, int* __restrict__ gcur,
                       int* __restrict__ total) {
    int i = blockIdx.x * blockDim.x + threadIdx.x;
    if (i < N_NODES) cnt[i] = 0;
    if (i < NB) gcur[i] = 0;
    if (i == 0) *total = 0;
}

// ---------------- W -> Wt bf16 (transposed, [col][k]) ----------------------
__global__ void k_wconv(const float* __restrict__ w, unsigned short* __restrict__ wt) {
    int t = threadIdx.x;
    for (int e = 0; e < 64; ++e) {
        int i = e * 256 + t;              // coalesced read
        int k = i >> 7, c = i & 127;
        wt[c * 128 + k] = f2bf(w[i]);
    }
}

// ---------------- in-degree count + per-edge position, 4 edges/thread ------
__global__ void k_count(const int* __restrict__ ei, const int* __restrict__ flag,
                        int* __restrict__ cnt, int* __restrict__ epos) {
    int t = blockIdx.x * blockDim.x + threadIdx.x;
    if (t >= N_EDGES / 4) return;
    int is64 = *flag;
    int d0, d1, d2, d3;
    if (is64) {
        const int4* pd = reinterpret_cast<const int4*>(ei) + N_EDGES / 2;
        int4 a = pd[2 * t], b = pd[2 * t + 1];
        d0 = a.x; d1 = a.z; d2 = b.x; d3 = b.z;
    } else {
        int4 v = reinterpret_cast<const int4*>(ei + N_EDGES)[t];
        d0 = v.x; d1 = v.y; d2 = v.z; d3 = v.w;
    }
    int4 p;
    p.x = atomicAdd(&cnt[d0], 1);
    p.y = atomicAdd(&cnt[d1], 1);
    p.z = atomicAdd(&cnt[d2], 1);
    p.w = atomicAdd(&cnt[d3], 1);
    reinterpret_cast<int4*>(epos)[t] = p;
}

// ---------------- dinv + segment offsets (wave scan) -----------------------
__global__ void k_offsets(const int* __restrict__ cnt, float* __restrict__ dinv,
                          int* __restrict__ row_start, int* __restrict__ total) {
    int i = blockIdx.x * blockDim.x + threadIdx.x;
    int lane = threadIdx.x & 63;
    int c = (i < N_NODES) ? cnt[i] : 0;
    if (i < N_NODES) dinv[i] = rsqrtf((float)(c + 1));   // +1 self loop
    int v = c;
#pragma unroll
    for (int d = 1; d < 64; d <<= 1) {
        int t = __shfl_up(v, d);
        if (lane >= d) v += t;
    }
    int base = 0;
    if (lane == 63) base = atomicAdd(total, v);
    base = __shfl(base, 63);
    if (i < N_NODES) row_start[i] = base + v - c;
}

// ---------------- bin: (src, final_idx) -> 32KB-window buckets --------------
// idx = row_start[d] + epos[e] is a permutation of [0, N_EDGES); bucket
// b = idx>>13 holds exactly 8192 entries (last: 2560). LDS staging + LDS
// histogram -> 1 global atomic per (block, bucket) -> dense append streams.
__global__ __launch_bounds__(256) void k_bin(const int* __restrict__ ei,
                                             const int* __restrict__ flag,
                                             const int* __restrict__ epos,
                                             const int* __restrict__ row_start,
                                             int* __restrict__ gcur,
                                             uint2* __restrict__ bucket) {
    __shared__ uint2 stage[BK_EDGES];
    __shared__ int hist[NB], lbase[NB], lcur[NB];
    const int tid = threadIdx.x;
    for (int b = tid; b < NB; b += 256) { hist[b] = 0; lcur[b] = 0; }
    __syncthreads();
    const int is64 = *flag;
    const int e0 = blockIdx.x * BK_EDGES;
    const int valid = min(BK_EDGES, N_EDGES - e0);

#pragma unroll
    for (int k = 0; k < 8; ++k) {
        int el = k * 512 + 2 * tid;
        if (el >= valid) break;
        int e = e0 + el;
        int s0, s1, d0, d1;
        if (is64) {
            int4 vs = reinterpret_cast<const int4*>(ei)[e >> 1];
            int4 vd = (reinterpret_cast<const int4*>(ei) + N_EDGES / 2)[e >> 1];
            s0 = vs.x; s1 = vs.z; d0 = vd.x; d1 = vd.z;
        } else {
            int2 vs = reinterpret_cast<const int2*>(ei)[e >> 1];
            int2 vd = reinterpret_cast<const int2*>(ei + N_EDGES)[e >> 1];
            s0 = vs.x; s1 = vs.y; d0 = vd.x; d1 = vd.y;
        }
        int2 p = reinterpret_cast<const int2*>(epos)[e >> 1];
        unsigned idx0 = (unsigned)(row_start[d0] + p.x);
        unsigned idx1 = (unsigned)(row_start[d1] + p.y);
        stage[el]     = make_uint2((unsigned)s0, idx0);
        stage[el + 1] = make_uint2((unsigned)s1, idx1);
        atomicAdd(&hist[idx0 >> 13], 1);
        atomicAdd(&hist[idx1 >> 13], 1);
    }
    __syncthreads();
    for (int b = tid; b < NB; b += 256)
        if (hist[b] > 0) lbase[b] = atomicAdd(&gcur[b], hist[b]);
    __syncthreads();
    for (int i = tid; i < valid; i += 256) {
        uint2 v = stage[i];
        int b = v.y >> 13;
        int pos = atomicAdd(&lcur[b], 1);
        bucket[((size_t)b << 13) + lbase[b] + pos] = v;
    }
}

// ---------------- scatter: bucket storage -> csr (L2-resident windows) -----
__global__ void k_scatter(const uint2* __restrict__ bucket, int* __restrict__ csr_src) {
    int g = blockIdx.x * blockDim.x + threadIdx.x;
    if (g >= N_EDGES) return;
    uint2 v = bucket[g];
    csr_src[v.y] = (int)v.x;
}

// ---------------- GEMM: h(bf16) = x(f32->bf16) @ W ------------------------
// BM=64 rows/block, 256 threads = 4 waves, each wave 16 rows x 128 cols.
// mfma_f32_16x16x32_bf16: A row=l&15, k=(l>>4)*8+j ; B col=l&15, same k ;
// D col=l&15, row=(l>>4)*4+reg  [per m89].
#define LDK 136   // padded bf16 row length (272 B -> 2-way LDS aliasing = free)
__global__ __launch_bounds__(256) void k_gemm(const float* __restrict__ x,
                                              const unsigned short* __restrict__ wt,
                                              unsigned short* __restrict__ h) {
    __shared__ unsigned short xs[64 * LDK];     // A tile  [row][k]
    __shared__ unsigned short ws[128 * LDK];    // B tile  [col][k] (Wt layout)
    const int tid = threadIdx.x;
    const int brow = blockIdx.x * 64;

    {   // stage x: 4 threads/row, 32 f32 each -> bf16
        int row = tid >> 2;
        int seg = (tid & 3) * 32;
        int grow = brow + row; if (grow > N_NODES - 1) grow = N_NODES - 1;
        const float4* p = reinterpret_cast<const float4*>(&x[(size_t)grow * IN_DIM + seg]);
#pragma unroll
        for (int i = 0; i < 8; ++i) {
            float4 v = p[i];
            ushort4 u = make_ushort4(f2bf(v.x), f2bf(v.y), f2bf(v.z), f2bf(v.w));
            *reinterpret_cast<ushort4*>(&xs[row * LDK + seg + i * 4]) = u;
        }
    }
    {   // stage Wt: 2 threads per 128-wide col-row, 64 bf16 each (8 x short8)
        int row = tid >> 1;
        int seg = (tid & 1) * 64;
        const short8* p = reinterpret_cast<const short8*>(&wt[row * 128 + seg]);
#pragma unroll
        for (int i = 0; i < 8; ++i)
            *reinterpret_cast<short8*>(&ws[row * LDK + seg + i * 8]) = p[i];
    }
    __syncthreads();

    const int lane = tid & 63;
    const int wid  = tid >> 6;
    const int m0   = wid * 16;
    const int arow = m0 + (lane & 15);
    const int kgrp = (lane >> 4) * 8;
    f32x4 acc[8] = {};

#pragma unroll
    for (int k0 = 0; k0 < 128; k0 += 32) {
        short8 a = *reinterpret_cast<const short8*>(&xs[arow * LDK + k0 + kgrp]);
#pragma unroll
        for (int nb = 0; nb < 8; ++nb) {
            short8 b = *reinterpret_cast<const short8*>(
                &ws[(nb * 16 + (lane & 15)) * LDK + k0 + kgrp]);
            acc[nb] = __builtin_amdgcn_mfma_f32_16x16x32_bf16(a, b, acc[nb], 0, 0, 0);
        }
    }

#pragma unroll
    for (int nb = 0; nb < 8; ++nb) {
#pragma unroll
        for (int r = 0; r < 4; ++r) {
            int node = brow + m0 + (lane >> 4) * 4 + r;
            int feat = nb * 16 + (lane & 15);
            if (node < N_NODES) h[(size_t)node * HID_DIM + feat] = f2bf(acc[nb][r]);
        }
    }
}

// ---------------- gather: 1 wave/node, 4 edges in flight, bf16 h -----------
__global__ __launch_bounds__(256) void k_gather(const unsigned short* __restrict__ h,
                                                const int* __restrict__ csr_src,
                                                const int* __restrict__ row_start,
                                                const int* __restrict__ cnt,
                                                const float* __restrict__ dinv,
                                                const float* __restrict__ bias,
                                                float* __restrict__ out) {
    int node = (blockIdx.x * blockDim.x + threadIdx.x) >> 6;
    if (node >= N_NODES) return;
    const int lane = threadIdx.x & 63;
    const int q  = lane >> 4;        // quarter: which edge slot this lane serves
    const int l4 = lane & 15;        // feature group: feats 8*l4 .. 8*l4+7
    const int rs = row_start[node];
    const int n  = cnt[node];
    const float di = dinv[node];
    const int total = n + 1;         // + self loop (virtual last slot)

    float acc[8] = {};

    for (int e0 = 0; e0 < total; e0 += 64) {
        int rem = total - e0;
        int m = rem < 64 ? rem : 64;
        // lane-parallel prefetch of up to 64 slot (src, weight) pairs
        int t = e0 + lane;
        int tt = t <= n ? t : n;
        int se; float dse;
        if (tt < n) { se = csr_src[rs + tt]; dse = dinv[se]; }
        else        { se = node;             dse = di; }     // self slot
        if (t > n) dse = 0.0f;                               // padding
        int mm = (m + 3) & ~3;
        for (int j = 0; j < mm; j += 4) {
            int   s  = __shfl(se,  j + q);
            float ds = __shfl(dse, j + q);
            short8 v = *reinterpret_cast<const short8*>(&h[(size_t)s * HID_DIM + l4 * 8]);
#pragma unroll
            for (int b = 0; b < 8; ++b)
                acc[b] = fmaf(ds, bf2f((unsigned short)v[b]), acc[b]);
        }
    }

    // combine the 4 quarters (each held partial sums for the same features)
#pragma unroll
    for (int b = 0; b < 8; ++b) {
        acc[b] += __shfl_xor(acc[b], 16);
        acc[b] += __shfl_xor(acc[b], 32);
    }

    if (q == 0) {
        float4 bv = *reinterpret_cast<const float4*>(&bias[l4 * 8]);
        float4 o;
        o.x = fmaxf(fmaf(di, acc[0], bv.x), 0.0f);
        o.y = fmaxf(fmaf(di, acc[1], bv.y), 0.0f);
        o.z = fmaxf(fmaf(di, acc[2], bv.z), 0.0f);
        o.w = fmaxf(fmaf(di, acc[3], bv.w), 0.0f);
        *reinterpret_cast<float4*>(&out[(size_t)node * HID_DIM + l4 * 8]) = o;
    } else if (q == 1) {
        float4 bv = *reinterpret_cast<const float4*>(&bias[l4 * 8 + 4]);
        float4 o;
        o.x = fmaxf(fmaf(di, acc[4], bv.x), 0.0f);
        o.y = fmaxf(fmaf(di, acc[5], bv.y), 0.0f);
        o.z = fmaxf(fmaf(di, acc[6], bv.z), 0.0f);
        o.w = fmaxf(fmaf(di, acc[7], bv.w), 0.0f);
        *reinterpret_cast<float4*>(&out[(size_t)node * HID_DIM + l4 * 8 + 4]) = o;
    }
}

// ---------------- launcher --------------------------------------------------
extern "C" void kernel_launch(void* const* d_in, const int* in_sizes, int n_in,
                              void* d_out, int out_size, void* d_ws, size_t ws_size,
                              hipStream_t stream) {
    const float* x    = (const float*)d_in[0];
    const int*   ei   = (const int*)d_in[1];
    const float* w    = (const float*)d_in[2];
    const float* bias = (const float*)d_in[3];
    float* out = (float*)d_out;

    // workspace layout (bytes), 16B-aligned; ~52.5 MB total
    char* wsb = (char*)d_ws;
    unsigned short* h  = (unsigned short*)(wsb);             // 25,600,000
    int*   cnt       = (int*)(wsb + 25600000);               // 400,000
    float* dinv      = (float*)(wsb + 26000000);             // 400,000
    int*   row_start = (int*)(wsb + 26400000);               // 400,000
    int*   epos      = (int*)(wsb + 26800000);               // 6,400,000
    int*   csr_src   = (int*)(wsb + 33200000);               // 6,400,000
    uint2* bucket    = (uint2*)(wsb + 39600000);             // 196*8192*8 = 12,845,056
    unsigned short* wt = (unsigned short*)(wsb + 52445056);  // 32,768
    int*   total     = (int*)(wsb + 52477824);               // 16
    int*   gcur      = (int*)(wsb + 52477840);               // 800
    int*   flag      = (int*)(wsb + 52478640);               // 16

    k_detect <<<1, 64, 0, stream>>>(ei, flag);
    k_init   <<<(N_NODES + 255) / 256, 256, 0, stream>>>(cnt, gcur, total);
    k_wconv  <<<1, 256, 0, stream>>>(w, wt);
    k_count  <<<(N_EDGES / 4 + 255) / 256, 256, 0, stream>>>(ei, flag, cnt, epos);
    k_offsets<<<(N_NODES + 255) / 256, 256, 0, stream>>>(cnt, dinv, row_start, total);
    k_bin    <<<(N_EDGES + BK_EDGES - 1) / BK_EDGES, 256, 0, stream>>>(ei, flag, epos, row_start, gcur, bucket);
    k_scatter<<<(N_EDGES + 255) / 256, 256, 0, stream>>>(bucket, csr_src);
    k_gemm   <<<(N_NODES + 63) / 64, 256, 0, stream>>>(x, wt, h);
    k_gather <<<(N_NODES + 3) / 4, 256, 0, stream>>>(h, csr_src, row_start, cnt, dinv, bias, out);
}

// Round 5
// 219.490 us; speedup vs baseline: 1.6872x; 1.1129x over previous
//
#include <hip/hip_runtime.h>
#include <hip/hip_bf16.h>

#define N_NODES 100000
#define IN_DIM 128
#define HID_DIM 128
#define N_EDGES 1600000
#define NB 196          // ceil(1.6e6 / 8192) buckets; each = 32KB csr window
#define BK_EDGES 4096   // edges staged per k_bin block

using short8 = __attribute__((ext_vector_type(8))) short;
using f32x4  = __attribute__((ext_vector_type(4))) float;

// ---- bf16 helpers (bit ops, RNE encode) ----------------------------------
__device__ __forceinline__ unsigned short f2bf(float f) {
    unsigned int b = __float_as_uint(f);
    b += 0x7FFFu + ((b >> 16) & 1u);
    return (unsigned short)(b >> 16);
}
__device__ __forceinline__ float bf2f(unsigned short u) {
    return __uint_as_float((unsigned int)u << 16);
}

// ---------------- prep: detect + init + wconv fused ------------------------
__global__ void k_prep(const int* __restrict__ ei, int* __restrict__ flag,
                       int* __restrict__ cnt, int* __restrict__ gcur,
                       int* __restrict__ total, const float* __restrict__ w,
                       unsigned short* __restrict__ wt) {
    int i = blockIdx.x * 256 + threadIdx.x;
    if (i < N_NODES) cnt[i] = 0;
    if (i < NB) gcur[i] = 0;
    if (i == 0) *total = 0;
    if (i < IN_DIM * HID_DIM) {            // W -> Wt bf16 transposed [col][k]
        int k = i >> 7, c = i & 127;
        wt[c * 128 + k] = f2bf(w[i]);
    }
    if (blockIdx.x == gridDim.x - 1 && threadIdx.x < 64) {
        int v = ei[2 * threadIdx.x + 1];   // int64 probe: odd words all zero
        int all0 = __all(v == 0);
        if (threadIdx.x == 0) *flag = all0;
    }
}

// ------ in-degree count + packed (pos<<17 | dst), 4 edges/thread -----------
// pos < 2^15 guaranteed (max in-degree of Poisson(16) over 100k nodes << 32768)
__global__ void k_count(const int* __restrict__ ei, const int* __restrict__ flag,
                        int* __restrict__ cnt, unsigned* __restrict__ epos) {
    int t = blockIdx.x * blockDim.x + threadIdx.x;
    if (t >= N_EDGES / 4) return;
    int is64 = *flag;
    int d0, d1, d2, d3;
    if (is64) {
        const int4* pd = reinterpret_cast<const int4*>(ei) + N_EDGES / 2;
        int4 a = pd[2 * t], b = pd[2 * t + 1];
        d0 = a.x; d1 = a.z; d2 = b.x; d3 = b.z;
    } else {
        int4 v = reinterpret_cast<const int4*>(ei + N_EDGES)[t];
        d0 = v.x; d1 = v.y; d2 = v.z; d3 = v.w;
    }
    uint4 p;
    p.x = ((unsigned)atomicAdd(&cnt[d0], 1) << 17) | (unsigned)d0;
    p.y = ((unsigned)atomicAdd(&cnt[d1], 1) << 17) | (unsigned)d1;
    p.z = ((unsigned)atomicAdd(&cnt[d2], 1) << 17) | (unsigned)d2;
    p.w = ((unsigned)atomicAdd(&cnt[d3], 1) << 17) | (unsigned)d3;
    reinterpret_cast<uint4*>(epos)[t] = p;
}

// ---------------- dinv + segment offsets (wave scan) -----------------------
__global__ void k_offsets(const int* __restrict__ cnt, float* __restrict__ dinv,
                          int* __restrict__ row_start, int* __restrict__ total) {
    int i = blockIdx.x * blockDim.x + threadIdx.x;
    int lane = threadIdx.x & 63;
    int c = (i < N_NODES) ? cnt[i] : 0;
    if (i < N_NODES) dinv[i] = rsqrtf((float)(c + 1));   // +1 self loop
    int v = c;
#pragma unroll
    for (int d = 1; d < 64; d <<= 1) {
        int t = __shfl_up(v, d);
        if (lane >= d) v += t;
    }
    int base = 0;
    if (lane == 63) base = atomicAdd(total, v);
    base = __shfl(base, 63);
    if (i < N_NODES) row_start[i] = base + v - c;
}

// ---------------- bin: (src, final_idx) -> 32KB-window buckets --------------
__global__ __launch_bounds__(256) void k_bin(const int* __restrict__ ei,
                                             const int* __restrict__ flag,
                                             const unsigned* __restrict__ epos,
                                             const int* __restrict__ row_start,
                                             int* __restrict__ gcur,
                                             uint2* __restrict__ bucket) {
    __shared__ uint2 stage[BK_EDGES];
    __shared__ int hist[NB], lbase[NB], lcur[NB];
    const int tid = threadIdx.x;
    for (int b = tid; b < NB; b += 256) { hist[b] = 0; lcur[b] = 0; }
    __syncthreads();
    const int is64 = *flag;
    const int e0 = blockIdx.x * BK_EDGES;
    const int valid = min(BK_EDGES, N_EDGES - e0);

#pragma unroll
    for (int k = 0; k < 8; ++k) {
        int el = k * 512 + 2 * tid;
        if (el >= valid) break;
        int e = e0 + el;
        int s0, s1;
        if (is64) {
            int4 vs = reinterpret_cast<const int4*>(ei)[e >> 1];
            s0 = vs.x; s1 = vs.z;
        } else {
            int2 vs = reinterpret_cast<const int2*>(ei)[e >> 1];
            s0 = vs.x; s1 = vs.y;
        }
        uint2 pk = reinterpret_cast<const uint2*>(epos)[e >> 1];
        int d0 = pk.x & 0x1FFFF, d1 = pk.y & 0x1FFFF;
        unsigned idx0 = (unsigned)row_start[d0] + (pk.x >> 17);
        unsigned idx1 = (unsigned)row_start[d1] + (pk.y >> 17);
        stage[el]     = make_uint2((unsigned)s0, idx0);
        stage[el + 1] = make_uint2((unsigned)s1, idx1);
        atomicAdd(&hist[idx0 >> 13], 1);
        atomicAdd(&hist[idx1 >> 13], 1);
    }
    __syncthreads();
    for (int b = tid; b < NB; b += 256)
        if (hist[b] > 0) lbase[b] = atomicAdd(&gcur[b], hist[b]);
    __syncthreads();
    for (int i = tid; i < valid; i += 256) {
        uint2 v = stage[i];
        int b = v.y >> 13;
        int pos = atomicAdd(&lcur[b], 1);
        bucket[((size_t)b << 13) + lbase[b] + pos] = v;
    }
}

// ---------------- scatter: bucket storage -> csr (L2-resident windows) -----
__global__ void k_scatter(const uint2* __restrict__ bucket, int* __restrict__ csr_src) {
    int g = blockIdx.x * blockDim.x + threadIdx.x;
    if (g >= N_EDGES) return;
    uint2 v = bucket[g];
    csr_src[v.y] = (int)v.x;
}

// ---------------- GEMM: h(bf16) = x(f32->bf16) @ W ------------------------
#define LDK 136   // padded bf16 row length
__global__ __launch_bounds__(256) void k_gemm(const float* __restrict__ x,
                                              const unsigned short* __restrict__ wt,
                                              unsigned short* __restrict__ h) {
    __shared__ unsigned short xs[64 * LDK];     // A tile  [row][k]
    __shared__ unsigned short ws[128 * LDK];    // B tile  [col][k] (Wt layout)
    const int tid = threadIdx.x;
    const int brow = blockIdx.x * 64;

    {   // stage x: 4 threads/row, 32 f32 each -> bf16
        int row = tid >> 2;
        int seg = (tid & 3) * 32;
        int grow = brow + row; if (grow > N_NODES - 1) grow = N_NODES - 1;
        const float4* p = reinterpret_cast<const float4*>(&x[(size_t)grow * IN_DIM + seg]);
#pragma unroll
        for (int i = 0; i < 8; ++i) {
            float4 v = p[i];
            ushort4 u = make_ushort4(f2bf(v.x), f2bf(v.y), f2bf(v.z), f2bf(v.w));
            *reinterpret_cast<ushort4*>(&xs[row * LDK + seg + i * 4]) = u;
        }
    }
    {   // stage Wt: 2 threads per 128-wide col-row, 64 bf16 each
        int row = tid >> 1;
        int seg = (tid & 1) * 64;
        const short8* p = reinterpret_cast<const short8*>(&wt[row * 128 + seg]);
#pragma unroll
        for (int i = 0; i < 8; ++i)
            *reinterpret_cast<short8*>(&ws[row * LDK + seg + i * 8]) = p[i];
    }
    __syncthreads();

    const int lane = tid & 63;
    const int wid  = tid >> 6;
    const int m0   = wid * 16;
    const int arow = m0 + (lane & 15);
    const int kgrp = (lane >> 4) * 8;
    f32x4 acc[8] = {};

#pragma unroll
    for (int k0 = 0; k0 < 128; k0 += 32) {
        short8 a = *reinterpret_cast<const short8*>(&xs[arow * LDK + k0 + kgrp]);
#pragma unroll
        for (int nb = 0; nb < 8; ++nb) {
            short8 b = *reinterpret_cast<const short8*>(
                &ws[(nb * 16 + (lane & 15)) * LDK + k0 + kgrp]);
            acc[nb] = __builtin_amdgcn_mfma_f32_16x16x32_bf16(a, b, acc[nb], 0, 0, 0);
        }
    }

#pragma unroll
    for (int nb = 0; nb < 8; ++nb) {
#pragma unroll
        for (int r = 0; r < 4; ++r) {
            int node = brow + m0 + (lane >> 4) * 4 + r;
            int feat = nb * 16 + (lane & 15);
            if (node < N_NODES) h[(size_t)node * HID_DIM + feat] = f2bf(acc[nb][r]);
        }
    }
}

// ------- gather: quarter-wave (16 lanes) per node, 16-deep unrolled --------
// 4 nodes per wave; each quarter prefetches 16 (src,dinv) slots then runs a
// fully-unrolled 16-step inner loop (compile-time shfl indices -> all loads
// issue early). Padding slots: weight 0, address = own row (L1-hot).
__global__ __launch_bounds__(256) void k_gather(const unsigned short* __restrict__ h,
                                                const int* __restrict__ csr_src,
                                                const int* __restrict__ row_start,
                                                const int* __restrict__ cnt,
                                                const float* __restrict__ dinv,
                                                const float* __restrict__ bias,
                                                float* __restrict__ out) {
    const int lane = threadIdx.x & 63;
    const int q    = lane >> 4;
    const int l4   = lane & 15;
    const int node = blockIdx.x * 16 + (threadIdx.x >> 6) * 4 + q;  // 6250*16 = 100000 exact
    const int rs = row_start[node];
    const int n  = cnt[node];
    const float di = dinv[node];
    const int tq = n + 1;                 // slots incl self loop

    float acc[8] = {};

    for (int c0 = 0; c0 < tq; c0 += 16) {
        int t = c0 + l4;
        int se; float dse;
        if (t < n)       { se = csr_src[rs + t]; dse = dinv[se]; }
        else if (t == n) { se = node; dse = di;   }
        else             { se = node; dse = 0.0f; }
#pragma unroll
        for (int j = 0; j < 16; ++j) {
            int   s  = __shfl(se,  (lane & 48) | j);
            float ds = __shfl(dse, (lane & 48) | j);
            short8 v = *reinterpret_cast<const short8*>(&h[(size_t)s * HID_DIM + l4 * 8]);
#pragma unroll
            for (int b = 0; b < 8; ++b)
                acc[b] = fmaf(ds, bf2f((unsigned short)v[b]), acc[b]);
        }
    }

    float4 bv0 = *reinterpret_cast<const float4*>(&bias[l4 * 8]);
    float4 bv1 = *reinterpret_cast<const float4*>(&bias[l4 * 8 + 4]);
    float4 o0, o1;
    o0.x = fmaxf(fmaf(di, acc[0], bv0.x), 0.0f);
    o0.y = fmaxf(fmaf(di, acc[1], bv0.y), 0.0f);
    o0.z = fmaxf(fmaf(di, acc[2], bv0.z), 0.0f);
    o0.w = fmaxf(fmaf(di, acc[3], bv0.w), 0.0f);
    o1.x = fmaxf(fmaf(di, acc[4], bv1.x), 0.0f);
    o1.y = fmaxf(fmaf(di, acc[5], bv1.y), 0.0f);
    o1.z = fmaxf(fmaf(di, acc[6], bv1.z), 0.0f);
    o1.w = fmaxf(fmaf(di, acc[7], bv1.w), 0.0f);
    *reinterpret_cast<float4*>(&out[(size_t)node * HID_DIM + l4 * 8])     = o0;
    *reinterpret_cast<float4*>(&out[(size_t)node * HID_DIM + l4 * 8 + 4]) = o1;
}

// ---------------- launcher --------------------------------------------------
extern "C" void kernel_launch(void* const* d_in, const int* in_sizes, int n_in,
                              void* d_out, int out_size, void* d_ws, size_t ws_size,
                              hipStream_t stream) {
    const float* x    = (const float*)d_in[0];
    const int*   ei   = (const int*)d_in[1];
    const float* w    = (const float*)d_in[2];
    const float* bias = (const float*)d_in[3];
    float* out = (float*)d_out;

    // workspace layout (bytes), 16B-aligned; ~52.5 MB total
    char* wsb = (char*)d_ws;
    unsigned short* h  = (unsigned short*)(wsb);             // 25,600,000
    int*   cnt       = (int*)(wsb + 25600000);               // 400,000
    float* dinv      = (float*)(wsb + 26000000);             // 400,000
    int*   row_start = (int*)(wsb + 26400000);               // 400,000
    unsigned* epos   = (unsigned*)(wsb + 26800000);          // 6,400,000
    int*   csr_src   = (int*)(wsb + 33200000);               // 6,400,000
    uint2* bucket    = (uint2*)(wsb + 39600000);             // 12,845,056
    unsigned short* wt = (unsigned short*)(wsb + 52445056);  // 32,768
    int*   total     = (int*)(wsb + 52477824);               // 16
    int*   gcur      = (int*)(wsb + 52477840);               // 800
    int*   flag      = (int*)(wsb + 52478640);               // 16

    k_prep   <<<(N_NODES + 255) / 256, 256, 0, stream>>>(ei, flag, cnt, gcur, total, w, wt);
    k_count  <<<(N_EDGES / 4 + 255) / 256, 256, 0, stream>>>(ei, flag, cnt, epos);
    k_offsets<<<(N_NODES + 255) / 256, 256, 0, stream>>>(cnt, dinv, row_start, total);
    k_bin    <<<(N_EDGES + BK_EDGES - 1) / BK_EDGES, 256, 0, stream>>>(ei, flag, epos, row_start, gcur, bucket);
    k_scatter<<<(N_EDGES + 255) / 256, 256, 0, stream>>>(bucket, csr_src);
    k_gemm   <<<(N_NODES + 63) / 64, 256, 0, stream>>>(x, wt, h);
    k_gather <<<N_NODES / 16, 256, 0, stream>>>(h, csr_src, row_start, cnt, dinv, bias, out);
}

// Round 6
// 139.176 us; speedup vs baseline: 2.6608x; 1.5771x over previous
//
#include <hip/hip_runtime.h>
#include <hip/hip_bf16.h>

#define N_NODES 100000
#define IN_DIM 128
#define HID_DIM 128
#define N_EDGES 1600000
#define NBK 196         // node buckets: 512 nodes each (196*512 = 100352)
#define BCAP 10240      // bucket capacity: E[sz]=8192, +22 sigma
#define BK_EDGES 4096   // edges staged per k_binA block

using short8 = __attribute__((ext_vector_type(8))) short;
using f32x4  = __attribute__((ext_vector_type(4))) float;

// ---- bf16 helpers (bit ops, RNE encode) ----------------------------------
__device__ __forceinline__ unsigned short f2bf(float f) {
    unsigned int b = __float_as_uint(f);
    b += 0x7FFFu + ((b >> 16) & 1u);
    return (unsigned short)(b >> 16);
}
__device__ __forceinline__ float bf2f(unsigned short u) {
    return __uint_as_float((unsigned int)u << 16);
}

// ---------------- prep: detect + init + wconv fused ------------------------
__global__ void k_prep(const int* __restrict__ ei, int* __restrict__ flag,
                       int* __restrict__ gcur, const float* __restrict__ w,
                       unsigned short* __restrict__ wt) {
    int i = blockIdx.x * 256 + threadIdx.x;
    if (i < NBK) gcur[i] = 0;
    if (i < IN_DIM * HID_DIM) {            // W -> Wt bf16 transposed [col][k]
        int k = i >> 7, c = i & 127;
        wt[c * 128 + k] = f2bf(w[i]);
    }
    if (blockIdx.x == gridDim.x - 1 && threadIdx.x < 64) {
        int v = ei[2 * threadIdx.x + 1];   // int64 probe: odd words all zero
        int all0 = __all(v == 0);
        if (threadIdx.x == 0) *flag = all0;
    }
}

// ------- binA: edges -> dst-window buckets, zero per-edge global atomics ---
__global__ __launch_bounds__(256) void k_binA(const int* __restrict__ ei,
                                              const int* __restrict__ flag,
                                              int* __restrict__ gcur,
                                              uint2* __restrict__ bucket) {
    __shared__ uint2 stage[BK_EDGES];
    __shared__ int hist[NBK], lbase[NBK], lcur[NBK];
    const int tid = threadIdx.x;
    for (int b = tid; b < NBK; b += 256) { hist[b] = 0; lcur[b] = 0; }
    __syncthreads();
    const int is64 = *flag;
    const int e0 = blockIdx.x * BK_EDGES;
    const int valid = min(BK_EDGES, N_EDGES - e0);

#pragma unroll
    for (int k = 0; k < 8; ++k) {
        int el = k * 512 + 2 * tid;
        if (el >= valid) break;
        int e = e0 + el;
        int s0, s1, d0, d1;
        if (is64) {
            int4 vs = reinterpret_cast<const int4*>(ei)[e >> 1];
            int4 vd = (reinterpret_cast<const int4*>(ei) + N_EDGES / 2)[e >> 1];
            s0 = vs.x; s1 = vs.z; d0 = vd.x; d1 = vd.z;
        } else {
            int2 vs = reinterpret_cast<const int2*>(ei)[e >> 1];
            int2 vd = reinterpret_cast<const int2*>(ei + N_EDGES)[e >> 1];
            s0 = vs.x; s1 = vs.y; d0 = vd.x; d1 = vd.y;
        }
        stage[el]     = make_uint2((unsigned)s0, (unsigned)d0);
        stage[el + 1] = make_uint2((unsigned)s1, (unsigned)d1);
        atomicAdd(&hist[d0 >> 9], 1);
        atomicAdd(&hist[d1 >> 9], 1);
    }
    __syncthreads();
    for (int b = tid; b < NBK; b += 256)
        if (hist[b] > 0) lbase[b] = atomicAdd(&gcur[b], hist[b]);
    __syncthreads();
    for (int i = tid; i < valid; i += 256) {
        uint2 v = stage[i];
        int b = v.y >> 9;
        int pos = lbase[b] + atomicAdd(&lcur[b], 1);
        if (pos < BCAP) bucket[(size_t)b * BCAP + pos] = v;
    }
}

// ------- buildB: one block per bucket -> cnt, dinv, row_start, csr ---------
__global__ __launch_bounds__(256) void k_buildB(const int* __restrict__ gcur,
                                                const uint2* __restrict__ bucket,
                                                int* __restrict__ cnt,
                                                float* __restrict__ dinv,
                                                int* __restrict__ row_start,
                                                int* __restrict__ csr_src) {
    __shared__ int sizes[NBK];
    __shared__ int ncnt[512], nloff[512], ncur[512];
    __shared__ int base_s, sz_s;
    const int b = blockIdx.x, tid = threadIdx.x;
    for (int i = tid; i < NBK; i += 256) sizes[i] = gcur[i];
    for (int i = tid; i < 512; i += 256) { ncnt[i] = 0; ncur[i] = 0; }
    __syncthreads();
    if (tid == 0) {
        int s = 0;
        for (int i = 0; i < b; ++i) s += sizes[i];
        base_s = s;
        sz_s = min(sizes[b], BCAP);
    }
    __syncthreads();
    const int base = base_s, sz = sz_s;
    const int n0 = b * 512;
    const uint2* bk = bucket + (size_t)b * BCAP;

    for (int i = tid; i < sz; i += 256)
        atomicAdd(&ncnt[bk[i].y - n0], 1);
    __syncthreads();
    if (tid == 0) {
        int s = 0;
        for (int i = 0; i < 512; ++i) { nloff[i] = s; s += ncnt[i]; }
    }
    __syncthreads();
    for (int i = tid; i < 512; i += 256) {
        int node = n0 + i;
        if (node < N_NODES) {
            int c = ncnt[i];
            cnt[node] = c;
            dinv[node] = rsqrtf((float)(c + 1));
            row_start[node] = base + nloff[i];
        }
    }
    for (int i = tid; i < sz; i += 256) {
        uint2 v = bk[i];                    // L2-hot second read
        int li = v.y - n0;
        int pos = atomicAdd(&ncur[li], 1);
        csr_src[base + nloff[li] + pos] = (int)v.x;
    }
}

// ---------------- GEMM: h(bf16) = x(f32->bf16) @ W ------------------------
#define LDK 136   // padded bf16 row length
__global__ __launch_bounds__(256) void k_gemm(const float* __restrict__ x,
                                              const unsigned short* __restrict__ wt,
                                              unsigned short* __restrict__ h) {
    __shared__ unsigned short xs[64 * LDK];     // A tile  [row][k]
    __shared__ unsigned short ws[128 * LDK];    // B tile  [col][k] (Wt layout)
    const int tid = threadIdx.x;
    const int brow = blockIdx.x * 64;

    {   // stage x: 4 threads/row, 32 f32 each -> bf16
        int row = tid >> 2;
        int seg = (tid & 3) * 32;
        int grow = brow + row; if (grow > N_NODES - 1) grow = N_NODES - 1;
        const float4* p = reinterpret_cast<const float4*>(&x[(size_t)grow * IN_DIM + seg]);
#pragma unroll
        for (int i = 0; i < 8; ++i) {
            float4 v = p[i];
            ushort4 u = make_ushort4(f2bf(v.x), f2bf(v.y), f2bf(v.z), f2bf(v.w));
            *reinterpret_cast<ushort4*>(&xs[row * LDK + seg + i * 4]) = u;
        }
    }
    {   // stage Wt: 2 threads per 128-wide col-row, 64 bf16 each
        int row = tid >> 1;
        int seg = (tid & 1) * 64;
        const short8* p = reinterpret_cast<const short8*>(&wt[row * 128 + seg]);
#pragma unroll
        for (int i = 0; i < 8; ++i)
            *reinterpret_cast<short8*>(&ws[row * LDK + seg + i * 8]) = p[i];
    }
    __syncthreads();

    const int lane = tid & 63;
    const int wid  = tid >> 6;
    const int m0   = wid * 16;
    const int arow = m0 + (lane & 15);
    const int kgrp = (lane >> 4) * 8;
    f32x4 acc[8] = {};

#pragma unroll
    for (int k0 = 0; k0 < 128; k0 += 32) {
        short8 a = *reinterpret_cast<const short8*>(&xs[arow * LDK + k0 + kgrp]);
#pragma unroll
        for (int nb = 0; nb < 8; ++nb) {
            short8 b = *reinterpret_cast<const short8*>(
                &ws[(nb * 16 + (lane & 15)) * LDK + k0 + kgrp]);
            acc[nb] = __builtin_amdgcn_mfma_f32_16x16x32_bf16(a, b, acc[nb], 0, 0, 0);
        }
    }

#pragma unroll
    for (int nb = 0; nb < 8; ++nb) {
#pragma unroll
        for (int r = 0; r < 4; ++r) {
            int node = brow + m0 + (lane >> 4) * 4 + r;
            int feat = nb * 16 + (lane & 15);
            if (node < N_NODES) h[(size_t)node * HID_DIM + feat] = f2bf(acc[nb][r]);
        }
    }
}

// ------- gather: quarter-wave (16 lanes) per node, 16-deep unrolled --------
__global__ __launch_bounds__(256) void k_gather(const unsigned short* __restrict__ h,
                                                const int* __restrict__ csr_src,
                                                const int* __restrict__ row_start,
                                                const int* __restrict__ cnt,
                                                const float* __restrict__ dinv,
                                                const float* __restrict__ bias,
                                                float* __restrict__ out) {
    const int lane = threadIdx.x & 63;
    const int l4   = lane & 15;
    const int node = blockIdx.x * 16 + (threadIdx.x >> 6) * 4 + (lane >> 4);
    const int rs = row_start[node];
    const int n  = cnt[node];
    const float di = dinv[node];
    const int tq = n + 1;                 // slots incl self loop

    float acc[8] = {};

    for (int c0 = 0; c0 < tq; c0 += 16) {
        int t = c0 + l4;
        int se; float dse;
        if (t < n)       { se = csr_src[rs + t]; dse = dinv[se]; }
        else if (t == n) { se = node; dse = di;   }
        else             { se = node; dse = 0.0f; }
#pragma unroll
        for (int j = 0; j < 16; ++j) {
            int   s  = __shfl(se,  (lane & 48) | j);
            float ds = __shfl(dse, (lane & 48) | j);
            short8 v = *reinterpret_cast<const short8*>(&h[(size_t)s * HID_DIM + l4 * 8]);
#pragma unroll
            for (int b = 0; b < 8; ++b)
                acc[b] = fmaf(ds, bf2f((unsigned short)v[b]), acc[b]);
        }
    }

    float4 bv0 = *reinterpret_cast<const float4*>(&bias[l4 * 8]);
    float4 bv1 = *reinterpret_cast<const float4*>(&bias[l4 * 8 + 4]);
    float4 o0, o1;
    o0.x = fmaxf(fmaf(di, acc[0], bv0.x), 0.0f);
    o0.y = fmaxf(fmaf(di, acc[1], bv0.y), 0.0f);
    o0.z = fmaxf(fmaf(di, acc[2], bv0.z), 0.0f);
    o0.w = fmaxf(fmaf(di, acc[3], bv0.w), 0.0f);
    o1.x = fmaxf(fmaf(di, acc[4], bv1.x), 0.0f);
    o1.y = fmaxf(fmaf(di, acc[5], bv1.y), 0.0f);
    o1.z = fmaxf(fmaf(di, acc[6], bv1.z), 0.0f);
    o1.w = fmaxf(fmaf(di, acc[7], bv1.w), 0.0f);
    *reinterpret_cast<float4*>(&out[(size_t)node * HID_DIM + l4 * 8])     = o0;
    *reinterpret_cast<float4*>(&out[(size_t)node * HID_DIM + l4 * 8 + 4]) = o1;
}

// ---------------- launcher --------------------------------------------------
extern "C" void kernel_launch(void* const* d_in, const int* in_sizes, int n_in,
                              void* d_out, int out_size, void* d_ws, size_t ws_size,
                              hipStream_t stream) {
    const float* x    = (const float*)d_in[0];
    const int*   ei   = (const int*)d_in[1];
    const float* w    = (const float*)d_in[2];
    const float* bias = (const float*)d_in[3];
    float* out = (float*)d_out;

    // workspace layout (bytes), 16B-aligned; ~49.3 MB total
    char* wsb = (char*)d_ws;
    unsigned short* h  = (unsigned short*)(wsb);             // 25,600,000
    int*   cnt       = (int*)(wsb + 25600000);               // 400,000
    float* dinv      = (float*)(wsb + 26000000);             // 400,000
    int*   row_start = (int*)(wsb + 26400000);               // 400,000
    int*   csr_src   = (int*)(wsb + 26800000);               // 6,400,000
    uint2* bucket    = (uint2*)(wsb + 33200000);             // 196*10240*8 = 16,056,320
    unsigned short* wt = (unsigned short*)(wsb + 49256320);  // 32,768
    int*   gcur      = (int*)(wsb + 49289088);               // 800
    int*   flag      = (int*)(wsb + 49289888);               // 16

    k_prep  <<<64, 256, 0, stream>>>(ei, flag, gcur, w, wt);
    k_binA  <<<(N_EDGES + BK_EDGES - 1) / BK_EDGES, 256, 0, stream>>>(ei, flag, gcur, bucket);
    k_buildB<<<NBK, 256, 0, stream>>>(gcur, bucket, cnt, dinv, row_start, csr_src);
    k_gemm  <<<(N_NODES + 63) / 64, 256, 0, stream>>>(x, wt, h);
    k_gather<<<N_NODES / 16, 256, 0, stream>>>(h, csr_src, row_start, cnt, dinv, bias, out);
}

// Round 7
// 125.761 us; speedup vs baseline: 2.9446x; 1.1067x over previous
//
#include <hip/hip_runtime.h>
#include <hip/hip_bf16.h>

#define N_NODES 100000
#define IN_DIM 128
#define HID_DIM 128
#define N_EDGES 1600000
#define NBK 196         // node buckets: 512 nodes each (196*512 = 100352)
#define BCAP 10240      // bucket capacity: E[sz]=8192, sigma~90, +22 sigma
#define BK_EDGES 4096   // edges staged per binA block
#define NBIN 391        // ceil(N_EDGES / BK_EDGES)
#define NGEMM 1563      // ceil(N_NODES / 64)
#define LDK 136         // padded fp16 row length in LDS

using half8 = __attribute__((ext_vector_type(8))) _Float16;
using half4 = __attribute__((ext_vector_type(4))) _Float16;
using f32x4 = __attribute__((ext_vector_type(4))) float;

// ---------------- prep: gcur zero + W -> Wt fp16 transposed [col][k] -------
__global__ void k_prep(int* __restrict__ gcur, const float* __restrict__ w,
                       _Float16* __restrict__ wt) {
    int i = blockIdx.x * 256 + threadIdx.x;
    if (i < NBK) gcur[i] = 0;
    if (i < IN_DIM * HID_DIM) {
        int k = i >> 7, c = i & 127;
        wt[c * 128 + k] = (_Float16)w[i];
    }
}

// ------------- fat1: blocks [0,NBIN) = binA ; [NBIN,NBIN+NGEMM) = gemm -----
__global__ __launch_bounds__(256) void k_fat1(const int* __restrict__ ei,
                                              const float* __restrict__ x,
                                              const _Float16* __restrict__ wt,
                                              _Float16* __restrict__ h,
                                              int* __restrict__ gcur,
                                              uint2* __restrict__ bucket) {
    __shared__ __align__(16) char smem[52224];
    const int tid = threadIdx.x;

    if (blockIdx.x < NBIN) {
        // ---------------- binA role: edges -> dst-window buckets ----------
        uint2* stage = (uint2*)smem;              // 32768 B
        int* hist  = (int*)(smem + 32768);        // 784 B
        int* lbase = (int*)(smem + 33552);
        int* lcur  = (int*)(smem + 34336);
        int* s64   = (int*)(smem + 35120);
        for (int b = tid; b < NBK; b += 256) { hist[b] = 0; lcur[b] = 0; }
        if (tid < 64) {                            // int64 layout probe
            int v = ei[2 * tid + 1];
            int all0 = __all(v == 0);
            if (tid == 0) *s64 = all0;
        }
        __syncthreads();
        const int is64 = *s64;
        const int e0 = blockIdx.x * BK_EDGES;
        const int valid = min(BK_EDGES, N_EDGES - e0);

#pragma unroll
        for (int k = 0; k < 8; ++k) {
            int el = k * 512 + 2 * tid;
            if (el >= valid) break;
            int e = e0 + el;
            int s0, s1, d0, d1;
            if (is64) {
                int4 vs = reinterpret_cast<const int4*>(ei)[e >> 1];
                int4 vd = (reinterpret_cast<const int4*>(ei) + N_EDGES / 2)[e >> 1];
                s0 = vs.x; s1 = vs.z; d0 = vd.x; d1 = vd.z;
            } else {
                int2 vs = reinterpret_cast<const int2*>(ei)[e >> 1];
                int2 vd = reinterpret_cast<const int2*>(ei + N_EDGES)[e >> 1];
                s0 = vs.x; s1 = vs.y; d0 = vd.x; d1 = vd.y;
            }
            stage[el]     = make_uint2((unsigned)s0, (unsigned)d0);
            stage[el + 1] = make_uint2((unsigned)s1, (unsigned)d1);
            atomicAdd(&hist[d0 >> 9], 1);
            atomicAdd(&hist[d1 >> 9], 1);
        }
        __syncthreads();
        for (int b = tid; b < NBK; b += 256)
            if (hist[b] > 0) lbase[b] = atomicAdd(&gcur[b], hist[b]);
        __syncthreads();
        for (int i = tid; i < valid; i += 256) {
            uint2 v = stage[i];
            int b = v.y >> 9;
            int pos = lbase[b] + atomicAdd(&lcur[b], 1);
            if (pos < BCAP) bucket[(size_t)b * BCAP + pos] = v;
        }
    } else {
        // ---------------- gemm role: h(fp16) = x @ W ----------------------
        _Float16* xs = (_Float16*)smem;            // 64*LDK*2  = 17408 B
        _Float16* ws = (_Float16*)(smem + 17408);  // 128*LDK*2 = 34816 B
        const int brow = (blockIdx.x - NBIN) * 64;
        {   // stage x: 4 threads/row, 32 f32 each -> fp16
            int row = tid >> 2;
            int seg = (tid & 3) * 32;
            int grow = brow + row; if (grow > N_NODES - 1) grow = N_NODES - 1;
            const float4* p = reinterpret_cast<const float4*>(&x[(size_t)grow * IN_DIM + seg]);
#pragma unroll
            for (int i = 0; i < 8; ++i) {
                float4 v = p[i];
                half4 hv = {(_Float16)v.x, (_Float16)v.y, (_Float16)v.z, (_Float16)v.w};
                *reinterpret_cast<half4*>(&xs[row * LDK + seg + i * 4]) = hv;
            }
        }
        {   // stage Wt: 2 threads per 128-wide col-row, 64 fp16 each
            int row = tid >> 1;
            int seg = (tid & 1) * 64;
            const half8* p = reinterpret_cast<const half8*>(&wt[row * 128 + seg]);
#pragma unroll
            for (int i = 0; i < 8; ++i)
                *reinterpret_cast<half8*>(&ws[row * LDK + seg + i * 8]) = p[i];
        }
        __syncthreads();

        const int lane = tid & 63;
        const int m0   = (tid >> 6) * 16;
        const int arow = m0 + (lane & 15);
        const int kgrp = (lane >> 4) * 8;
        f32x4 acc[8] = {};
#pragma unroll
        for (int k0 = 0; k0 < 128; k0 += 32) {
            half8 a = *reinterpret_cast<const half8*>(&xs[arow * LDK + k0 + kgrp]);
#pragma unroll
            for (int nb = 0; nb < 8; ++nb) {
                half8 b = *reinterpret_cast<const half8*>(
                    &ws[(nb * 16 + (lane & 15)) * LDK + k0 + kgrp]);
                acc[nb] = __builtin_amdgcn_mfma_f32_16x16x32_f16(a, b, acc[nb], 0, 0, 0);
            }
        }
#pragma unroll
        for (int nb = 0; nb < 8; ++nb) {
#pragma unroll
            for (int r = 0; r < 4; ++r) {
                int node = brow + m0 + (lane >> 4) * 4 + r;
                int feat = nb * 16 + (lane & 15);
                if (node < N_NODES) h[(size_t)node * HID_DIM + feat] = (_Float16)acc[nb][r];
            }
        }
    }
}

// ------- buildB: one block per bucket -> cnt, dinv, row_start, csr ---------
__global__ __launch_bounds__(256) void k_buildB(const int* __restrict__ gcur,
                                                const uint2* __restrict__ bucket,
                                                int* __restrict__ cnt,
                                                float* __restrict__ dinv,
                                                int* __restrict__ row_start,
                                                int* __restrict__ csr_src) {
    __shared__ int sizes[NBK];
    __shared__ int ncnt[512], nloff[512], ncur[512];
    __shared__ int wtot[4];
    __shared__ int base_s;
    const int b = blockIdx.x, tid = threadIdx.x;
    for (int i = tid; i < NBK; i += 256) sizes[i] = gcur[i];
    ncnt[tid] = 0; ncnt[tid + 256] = 0; ncur[tid] = 0; ncur[tid + 256] = 0;
    __syncthreads();
    const int sz = min(sizes[b], BCAP);
    if (tid < 64) {                 // wave-parallel: base = sum sizes[0..b)
        int part = 0;
        for (int i = tid; i < b; i += 64) part += sizes[i];
#pragma unroll
        for (int d = 32; d; d >>= 1) part += __shfl_xor(part, d);
        if (tid == 0) base_s = part;
    }
    const int n0 = b * 512;
    const uint2* bk = bucket + (size_t)b * BCAP;
    for (int i = tid; i < sz; i += 256) atomicAdd(&ncnt[bk[i].y - n0], 1);
    __syncthreads();
    // 2-level exclusive scan over ncnt[512]: thread owns 2 consecutive
    int c0 = ncnt[2 * tid], c1 = ncnt[2 * tid + 1];
    int pair = c0 + c1;
    int lane = tid & 63, wv = tid >> 6;
    int scan = pair;
#pragma unroll
    for (int d = 1; d < 64; d <<= 1) {
        int t = __shfl_up(scan, d);
        if (lane >= d) scan += t;
    }
    if (lane == 63) wtot[wv] = scan;
    int excl = scan - pair;
    __syncthreads();
#pragma unroll
    for (int i = 0; i < 4; ++i) if (i < wv) excl += wtot[i];
    nloff[2 * tid] = excl;
    nloff[2 * tid + 1] = excl + c0;
    __syncthreads();
    const int base = base_s;
    for (int i = tid; i < 512; i += 256) {
        int node = n0 + i;
        if (node < N_NODES) {
            int c = ncnt[i];
            cnt[node] = c;
            dinv[node] = rsqrtf((float)(c + 1));
            row_start[node] = base + nloff[i];
        }
    }
    for (int i = tid; i < sz; i += 256) {
        uint2 v = bk[i];
        int li = v.y - n0;
        int pos = atomicAdd(&ncur[li], 1);
        csr_src[base + nloff[li] + pos] = (int)v.x;
    }
}

// ------- gather: 16 lanes/node, chunk-32 prefetch, early-exit per 8 --------
#define GSTEP(J, SE, DS) {                                                   \
    int s_ = __shfl(SE, hi | (J));                                           \
    float w_ = __shfl(DS, hi | (J));                                         \
    half8 v_ = *reinterpret_cast<const half8*>(hbase + (size_t)s_ * HID_DIM);\
    acc[0] = fmaf((float)v_[0], w_, acc[0]);                                 \
    acc[1] = fmaf((float)v_[1], w_, acc[1]);                                 \
    acc[2] = fmaf((float)v_[2], w_, acc[2]);                                 \
    acc[3] = fmaf((float)v_[3], w_, acc[3]);                                 \
    acc[4] = fmaf((float)v_[4], w_, acc[4]);                                 \
    acc[5] = fmaf((float)v_[5], w_, acc[5]);                                 \
    acc[6] = fmaf((float)v_[6], w_, acc[6]);                                 \
    acc[7] = fmaf((float)v_[7], w_, acc[7]); }
#define GGRP(B, SE, DS) \
    GSTEP(B + 0, SE, DS) GSTEP(B + 1, SE, DS) GSTEP(B + 2, SE, DS) \
    GSTEP(B + 3, SE, DS) GSTEP(B + 4, SE, DS) GSTEP(B + 5, SE, DS) \
    GSTEP(B + 6, SE, DS) GSTEP(B + 7, SE, DS)

__global__ __launch_bounds__(256) void k_gather(const _Float16* __restrict__ h,
                                                const int* __restrict__ csr_src,
                                                const int* __restrict__ row_start,
                                                const int* __restrict__ cnt,
                                                const float* __restrict__ dinv,
                                                const float* __restrict__ bias,
                                                float* __restrict__ out) {
    const int lane = threadIdx.x & 63;
    const int l4   = lane & 15;
    const int hi   = lane & 48;
    const int node = blockIdx.x * 16 + (threadIdx.x >> 6) * 4 + (lane >> 4);
    const int rs = row_start[node];
    const int n  = cnt[node];
    const float di = dinv[node];
    const int tq = n + 1;                 // slots incl self loop
    const _Float16* hbase = h + l4 * 8;

    float acc[8] = {};

    for (int c0 = 0; c0 < tq; c0 += 32) {
        int t0 = c0 + l4, t1 = t0 + 16;
        int se0 = node, se1 = node;
        float dw0 = 0.0f, dw1 = 0.0f;
        if (t0 < n)       { se0 = csr_src[rs + t0]; dw0 = dinv[se0]; }
        else if (t0 == n)   dw0 = di;
        if (t1 < n)       { se1 = csr_src[rs + t1]; dw1 = dinv[se1]; }
        else if (t1 == n)   dw1 = di;

        GGRP(0, se0, dw0)
        if (tq <= c0 + 8) continue;
        GGRP(8, se0, dw0)
        if (tq <= c0 + 16) continue;
        GGRP(0, se1, dw1)
        if (tq <= c0 + 24) continue;
        GGRP(8, se1, dw1)
    }

    float4 bv0 = *reinterpret_cast<const float4*>(&bias[l4 * 8]);
    float4 bv1 = *reinterpret_cast<const float4*>(&bias[l4 * 8 + 4]);
    float4 o0, o1;
    o0.x = fmaxf(fmaf(di, acc[0], bv0.x), 0.0f);
    o0.y = fmaxf(fmaf(di, acc[1], bv0.y), 0.0f);
    o0.z = fmaxf(fmaf(di, acc[2], bv0.z), 0.0f);
    o0.w = fmaxf(fmaf(di, acc[3], bv0.w), 0.0f);
    o1.x = fmaxf(fmaf(di, acc[4], bv1.x), 0.0f);
    o1.y = fmaxf(fmaf(di, acc[5], bv1.y), 0.0f);
    o1.z = fmaxf(fmaf(di, acc[6], bv1.z), 0.0f);
    o1.w = fmaxf(fmaf(di, acc[7], bv1.w), 0.0f);
    *reinterpret_cast<float4*>(&out[(size_t)node * HID_DIM + l4 * 8])     = o0;
    *reinterpret_cast<float4*>(&out[(size_t)node * HID_DIM + l4 * 8 + 4]) = o1;
}

// ---------------- launcher --------------------------------------------------
extern "C" void kernel_launch(void* const* d_in, const int* in_sizes, int n_in,
                              void* d_out, int out_size, void* d_ws, size_t ws_size,
                              hipStream_t stream) {
    const float* x    = (const float*)d_in[0];
    const int*   ei   = (const int*)d_in[1];
    const float* w    = (const float*)d_in[2];
    const float* bias = (const float*)d_in[3];
    float* out = (float*)d_out;

    // workspace layout (bytes), 16B-aligned; ~49.3 MB total
    char* wsb = (char*)d_ws;
    _Float16* h      = (_Float16*)(wsb);                  // 25,600,000
    int*   cnt       = (int*)(wsb + 25600000);            // 400,000
    float* dinv      = (float*)(wsb + 26000000);          // 400,000
    int*   row_start = (int*)(wsb + 26400000);            // 400,000
    int*   csr_src   = (int*)(wsb + 26800000);            // 6,400,000
    uint2* bucket    = (uint2*)(wsb + 33200000);          // 196*10240*8 = 16,056,320
    _Float16* wt     = (_Float16*)(wsb + 49256320);       // 32,768
    int*   gcur      = (int*)(wsb + 49289088);            // 800

    k_prep  <<<64, 256, 0, stream>>>(gcur, w, wt);
    k_fat1  <<<NBIN + NGEMM, 256, 0, stream>>>(ei, x, wt, h, gcur, bucket);
    k_buildB<<<NBK, 256, 0, stream>>>(gcur, bucket, cnt, dinv, row_start, csr_src);
    k_gather<<<N_NODES / 16, 256, 0, stream>>>(h, csr_src, row_start, cnt, dinv, bias, out);
}

// Round 8
// 123.295 us; speedup vs baseline: 3.0035x; 1.0200x over previous
//
#include <hip/hip_runtime.h>
#include <hip/hip_bf16.h>

#define N_NODES 100000
#define IN_DIM 128
#define HID_DIM 128
#define N_EDGES 1600000
#define NBK 196         // node buckets: 512 nodes each (196*512 = 100352)
#define BCAP 10240      // bucket capacity: E[sz]=8192, sigma~90, +22 sigma
#define BK_EDGES 4096   // edges staged per binA block
#define NBIN 391        // ceil(N_EDGES / BK_EDGES)
#define NGEMM 1563      // ceil(N_NODES / 64)
#define G1 625          // gemm blocks co-launched with binA (rows [0,40000))
#define G2 (NGEMM - G1) // gemm blocks co-launched with buildB
#define LDK 136         // padded fp16 row length in LDS

using half8 = __attribute__((ext_vector_type(8))) _Float16;
using half4 = __attribute__((ext_vector_type(4))) _Float16;
using f32x4 = __attribute__((ext_vector_type(4))) float;

// ---------------- prep: gcur zero + W -> Wt fp16 transposed [col][k] -------
__global__ void k_prep(int* __restrict__ gcur, const float* __restrict__ w,
                       _Float16* __restrict__ wt) {
    int i = blockIdx.x * 256 + threadIdx.x;
    if (i < NBK) gcur[i] = 0;
    if (i < IN_DIM * HID_DIM) {
        int k = i >> 7, c = i & 127;
        wt[c * 128 + k] = (_Float16)w[i];
    }
}

// ---------------- gemm role (device fn): h[brow..brow+64) = x @ W ----------
__device__ __forceinline__ void gemm_role(char* smem, int tid, int brow,
                                          const float* __restrict__ x,
                                          const _Float16* __restrict__ wt,
                                          _Float16* __restrict__ h) {
    _Float16* xs = (_Float16*)smem;            // 64*LDK*2  = 17408 B
    _Float16* ws = (_Float16*)(smem + 17408);  // 128*LDK*2 = 34816 B
    {   // stage x: 4 threads/row, 32 f32 each -> fp16
        int row = tid >> 2;
        int seg = (tid & 3) * 32;
        int grow = brow + row; if (grow > N_NODES - 1) grow = N_NODES - 1;
        const float4* p = reinterpret_cast<const float4*>(&x[(size_t)grow * IN_DIM + seg]);
#pragma unroll
        for (int i = 0; i < 8; ++i) {
            float4 v = p[i];
            half4 hv = {(_Float16)v.x, (_Float16)v.y, (_Float16)v.z, (_Float16)v.w};
            *reinterpret_cast<half4*>(&xs[row * LDK + seg + i * 4]) = hv;
        }
    }
    {   // stage Wt: 2 threads per 128-wide col-row, 64 fp16 each
        int row = tid >> 1;
        int seg = (tid & 1) * 64;
        const half8* p = reinterpret_cast<const half8*>(&wt[row * 128 + seg]);
#pragma unroll
        for (int i = 0; i < 8; ++i)
            *reinterpret_cast<half8*>(&ws[row * LDK + seg + i * 8]) = p[i];
    }
    __syncthreads();

    const int lane = tid & 63;
    const int m0   = (tid >> 6) * 16;
    const int arow = m0 + (lane & 15);
    const int kgrp = (lane >> 4) * 8;
    f32x4 acc[8] = {};
#pragma unroll
    for (int k0 = 0; k0 < 128; k0 += 32) {
        half8 a = *reinterpret_cast<const half8*>(&xs[arow * LDK + k0 + kgrp]);
#pragma unroll
        for (int nb = 0; nb < 8; ++nb) {
            half8 b = *reinterpret_cast<const half8*>(
                &ws[(nb * 16 + (lane & 15)) * LDK + k0 + kgrp]);
            acc[nb] = __builtin_amdgcn_mfma_f32_16x16x32_f16(a, b, acc[nb], 0, 0, 0);
        }
    }
#pragma unroll
    for (int nb = 0; nb < 8; ++nb) {
#pragma unroll
        for (int r = 0; r < 4; ++r) {
            int node = brow + m0 + (lane >> 4) * 4 + r;
            int feat = nb * 16 + (lane & 15);
            if (node < N_NODES) h[(size_t)node * HID_DIM + feat] = (_Float16)acc[nb][r];
        }
    }
}

// ------------- k1: blocks [0,NBIN) = binA ; [NBIN,NBIN+G1) = gemm ----------
__global__ __launch_bounds__(256) void k_fat1(const int* __restrict__ ei,
                                              const float* __restrict__ x,
                                              const _Float16* __restrict__ wt,
                                              _Float16* __restrict__ h,
                                              int* __restrict__ gcur,
                                              uint2* __restrict__ bucket) {
    __shared__ __align__(16) char smem[52224];
    const int tid = threadIdx.x;

    if (blockIdx.x >= NBIN) {
        gemm_role(smem, tid, (blockIdx.x - NBIN) * 64, x, wt, h);
        return;
    }
    // ---------------- binA role: edges -> dst-window buckets --------------
    uint2* stage = (uint2*)smem;              // 32768 B
    int* hist  = (int*)(smem + 32768);
    int* lbase = (int*)(smem + 33552);
    int* lcur  = (int*)(smem + 34336);
    int* s64   = (int*)(smem + 35120);
    for (int b = tid; b < NBK; b += 256) { hist[b] = 0; lcur[b] = 0; }
    if (tid < 64) {                            // int64 layout probe
        int v = ei[2 * tid + 1];
        int all0 = __all(v == 0);
        if (tid == 0) *s64 = all0;
    }
    __syncthreads();
    const int is64 = *s64;
    const int e0 = blockIdx.x * BK_EDGES;
    const int valid = min(BK_EDGES, N_EDGES - e0);

#pragma unroll
    for (int k = 0; k < 8; ++k) {
        int el = k * 512 + 2 * tid;
        if (el >= valid) break;
        int e = e0 + el;
        int s0, s1, d0, d1;
        if (is64) {
            int4 vs = reinterpret_cast<const int4*>(ei)[e >> 1];
            int4 vd = (reinterpret_cast<const int4*>(ei) + N_EDGES / 2)[e >> 1];
            s0 = vs.x; s1 = vs.z; d0 = vd.x; d1 = vd.z;
        } else {
            int2 vs = reinterpret_cast<const int2*>(ei)[e >> 1];
            int2 vd = reinterpret_cast<const int2*>(ei + N_EDGES)[e >> 1];
            s0 = vs.x; s1 = vs.y; d0 = vd.x; d1 = vd.y;
        }
        stage[el]     = make_uint2((unsigned)s0, (unsigned)d0);
        stage[el + 1] = make_uint2((unsigned)s1, (unsigned)d1);
        atomicAdd(&hist[d0 >> 9], 1);
        atomicAdd(&hist[d1 >> 9], 1);
    }
    __syncthreads();
    for (int b = tid; b < NBK; b += 256)
        if (hist[b] > 0) lbase[b] = atomicAdd(&gcur[b], hist[b]);
    __syncthreads();
    for (int i = tid; i < valid; i += 256) {
        uint2 v = stage[i];
        int b = v.y >> 9;
        int pos = lbase[b] + atomicAdd(&lcur[b], 1);
        if (pos < BCAP) bucket[(size_t)b * BCAP + pos] = v;
    }
}

// ------------- k2: blocks [0,NBK) = buildB ; [NBK,NBK+G2) = gemm -----------
__global__ __launch_bounds__(256) void k_fat2(const int* __restrict__ gcur,
                                              const uint2* __restrict__ bucket,
                                              int* __restrict__ cnt,
                                              float* __restrict__ dinv,
                                              int* __restrict__ row_start,
                                              int* __restrict__ csr_src,
                                              const float* __restrict__ x,
                                              const _Float16* __restrict__ wt,
                                              _Float16* __restrict__ h) {
    __shared__ __align__(16) char smem[52224];
    const int tid = threadIdx.x;

    if (blockIdx.x >= NBK) {
        gemm_role(smem, tid, (G1 + blockIdx.x - NBK) * 64, x, wt, h);
        return;
    }
    // ---------------- buildB role ------------------------------------------
    int* sizes = (int*)smem;                   // 784 B
    int* ncnt  = (int*)(smem + 784);           // 2048
    int* nloff = (int*)(smem + 2832);          // 2048
    int* ncur  = (int*)(smem + 4880);          // 2048
    int* wtot  = (int*)(smem + 6928);          // 16
    int* base_p = (int*)(smem + 6944);
    const int b = blockIdx.x;
    for (int i = tid; i < NBK; i += 256) sizes[i] = gcur[i];
    ncnt[tid] = 0; ncnt[tid + 256] = 0; ncur[tid] = 0; ncur[tid + 256] = 0;
    __syncthreads();
    const int sz = min(sizes[b], BCAP);
    if (tid < 64) {                 // wave-parallel: base = sum sizes[0..b)
        int part = 0;
        for (int i = tid; i < b; i += 64) part += sizes[i];
#pragma unroll
        for (int d = 32; d; d >>= 1) part += __shfl_xor(part, d);
        if (tid == 0) *base_p = part;
    }
    const int n0 = b * 512;
    const uint2* bk = bucket + (size_t)b * BCAP;
    for (int i = tid; i < sz; i += 256) atomicAdd(&ncnt[bk[i].y - n0], 1);
    __syncthreads();
    // 2-level exclusive scan over ncnt[512]: thread owns 2 consecutive
    int c0 = ncnt[2 * tid], c1 = ncnt[2 * tid + 1];
    int pair = c0 + c1;
    int lane = tid & 63, wv = tid >> 6;
    int scan = pair;
#pragma unroll
    for (int d = 1; d < 64; d <<= 1) {
        int t = __shfl_up(scan, d);
        if (lane >= d) scan += t;
    }
    if (lane == 63) wtot[wv] = scan;
    int excl = scan - pair;
    __syncthreads();
#pragma unroll
    for (int i = 0; i < 4; ++i) if (i < wv) excl += wtot[i];
    nloff[2 * tid] = excl;
    nloff[2 * tid + 1] = excl + c0;
    __syncthreads();
    const int base = *base_p;
    for (int i = tid; i < 512; i += 256) {
        int node = n0 + i;
        if (node < N_NODES) {
            int c = ncnt[i];
            cnt[node] = c;
            dinv[node] = rsqrtf((float)(c + 1));
            row_start[node] = base + nloff[i];
        }
    }
    for (int i = tid; i < sz; i += 256) {
        uint2 v = bk[i];
        int li = v.y - n0;
        int pos = atomicAdd(&ncur[li], 1);
        csr_src[base + nloff[li] + pos] = (int)v.x;
    }
}

// ------- gather: 16 lanes/node, chunk-32 prefetch, early-exit per 8 --------
#define GSTEP(J, SE, DS) {                                                   \
    int s_ = __shfl(SE, hi | (J));                                           \
    float w_ = __shfl(DS, hi | (J));                                         \
    half8 v_ = *reinterpret_cast<const half8*>(hbase + (size_t)s_ * HID_DIM);\
    acc[0] = fmaf((float)v_[0], w_, acc[0]);                                 \
    acc[1] = fmaf((float)v_[1], w_, acc[1]);                                 \
    acc[2] = fmaf((float)v_[2], w_, acc[2]);                                 \
    acc[3] = fmaf((float)v_[3], w_, acc[3]);                                 \
    acc[4] = fmaf((float)v_[4], w_, acc[4]);                                 \
    acc[5] = fmaf((float)v_[5], w_, acc[5]);                                 \
    acc[6] = fmaf((float)v_[6], w_, acc[6]);                                 \
    acc[7] = fmaf((float)v_[7], w_, acc[7]); }
#define GGRP(B, SE, DS) \
    GSTEP(B + 0, SE, DS) GSTEP(B + 1, SE, DS) GSTEP(B + 2, SE, DS) \
    GSTEP(B + 3, SE, DS) GSTEP(B + 4, SE, DS) GSTEP(B + 5, SE, DS) \
    GSTEP(B + 6, SE, DS) GSTEP(B + 7, SE, DS)

__global__ __launch_bounds__(256) void k_gather(const _Float16* __restrict__ h,
                                                const int* __restrict__ csr_src,
                                                const int* __restrict__ row_start,
                                                const int* __restrict__ cnt,
                                                const float* __restrict__ dinv,
                                                const float* __restrict__ bias,
                                                float* __restrict__ out) {
    const int lane = threadIdx.x & 63;
    const int l4   = lane & 15;
    const int hi   = lane & 48;
    const int node = blockIdx.x * 16 + (threadIdx.x >> 6) * 4 + (lane >> 4);
    const int rs = row_start[node];
    const int n  = cnt[node];
    const float di = dinv[node];
    const int tq = n + 1;                 // slots incl self loop
    const _Float16* hbase = h + l4 * 8;

    float acc[8] = {};

    for (int c0 = 0; c0 < tq; c0 += 32) {
        int t0 = c0 + l4, t1 = t0 + 16;
        int se0 = node, se1 = node;
        float dw0 = 0.0f, dw1 = 0.0f;
        if (t0 < n)       { se0 = csr_src[rs + t0]; dw0 = dinv[se0]; }
        else if (t0 == n)   dw0 = di;
        if (t1 < n)       { se1 = csr_src[rs + t1]; dw1 = dinv[se1]; }
        else if (t1 == n)   dw1 = di;

        GGRP(0, se0, dw0)
        if (tq <= c0 + 8) continue;
        GGRP(8, se0, dw0)
        if (tq <= c0 + 16) continue;
        GGRP(0, se1, dw1)
        if (tq <= c0 + 24) continue;
        GGRP(8, se1, dw1)
    }

    float4 bv0 = *reinterpret_cast<const float4*>(&bias[l4 * 8]);
    float4 bv1 = *reinterpret_cast<const float4*>(&bias[l4 * 8 + 4]);
    float4 o0, o1;
    o0.x = fmaxf(fmaf(di, acc[0], bv0.x), 0.0f);
    o0.y = fmaxf(fmaf(di, acc[1], bv0.y), 0.0f);
    o0.z = fmaxf(fmaf(di, acc[2], bv0.z), 0.0f);
    o0.w = fmaxf(fmaf(di, acc[3], bv0.w), 0.0f);
    o1.x = fmaxf(fmaf(di, acc[4], bv1.x), 0.0f);
    o1.y = fmaxf(fmaf(di, acc[5], bv1.y), 0.0f);
    o1.z = fmaxf(fmaf(di, acc[6], bv1.z), 0.0f);
    o1.w = fmaxf(fmaf(di, acc[7], bv1.w), 0.0f);
    *reinterpret_cast<float4*>(&out[(size_t)node * HID_DIM + l4 * 8])     = o0;
    *reinterpret_cast<float4*>(&out[(size_t)node * HID_DIM + l4 * 8 + 4]) = o1;
}

// ---------------- launcher --------------------------------------------------
extern "C" void kernel_launch(void* const* d_in, const int* in_sizes, int n_in,
                              void* d_out, int out_size, void* d_ws, size_t ws_size,
                              hipStream_t stream) {
    const float* x    = (const float*)d_in[0];
    const int*   ei   = (const int*)d_in[1];
    const float* w    = (const float*)d_in[2];
    const float* bias = (const float*)d_in[3];
    float* out = (float*)d_out;

    // workspace layout (bytes), 16B-aligned; ~49.3 MB total
    char* wsb = (char*)d_ws;
    _Float16* h      = (_Float16*)(wsb);                  // 25,600,000
    int*   cnt       = (int*)(wsb + 25600000);            // 400,000
    float* dinv      = (float*)(wsb + 26000000);          // 400,000
    int*   row_start = (int*)(wsb + 26400000);            // 400,000
    int*   csr_src   = (int*)(wsb + 26800000);            // 6,400,000
    uint2* bucket    = (uint2*)(wsb + 33200000);          // 196*10240*8 = 16,056,320
    _Float16* wt     = (_Float16*)(wsb + 49256320);       // 32,768
    int*   gcur      = (int*)(wsb + 49289088);            // 800

    k_prep  <<<64, 256, 0, stream>>>(gcur, w, wt);
    k_fat1  <<<NBIN + G1, 256, 0, stream>>>(ei, x, wt, h, gcur, bucket);
    k_fat2  <<<NBK + G2, 256, 0, stream>>>(gcur, bucket, cnt, dinv, row_start, csr_src, x, wt, h);
    k_gather<<<N_NODES / 16, 256, 0, stream>>>(h, csr_src, row_start, cnt, dinv, bias, out);
}